// Round 5
// baseline (1189.290 us; speedup 1.0000x reference)
//
#include <hip/hip_runtime.h>
#include <math.h>

#define N_ATOMS 50000
#define N_PAIRS 1600000
#define NF 128
#define NRBF 20
#define NTILES (N_PAIRS / 64)   // 25000

typedef _Float16 half8 __attribute__((ext_vector_type(8)));
typedef _Float16 half2t __attribute__((ext_vector_type(2)));
typedef float floatx4 __attribute__((ext_vector_type(4)));

__device__ __forceinline__ float sspf(float x) {
    float t = __expf(-fabsf(x));
    return fmaxf(x, 0.0f) + __logf(1.0f + t) - 0.69314718055994530942f;
}

// Swizzled LDS layout for [128 x 128 fp16] (256 B rows): 16B group k8 of row r at (k8 ^ (r&15)).
__device__ __forceinline__ int swz16(int row, int k8) {
    return row * 256 + ((k8 ^ (row & 15)) << 4);
}

// Stage fp32 W[k][c] -> LDS fp16 transposed [c][k], swizzled. Paired-k: one 4B write per 2 elems.
template<int NTHR>
__device__ __forceinline__ void stage_w(const float* __restrict__ W, char* dst, int t) {
    for (int i = t; i < 64 * 128; i += NTHR) {
        int k2 = i >> 7, c = i & 127;
        int k = k2 * 2;
        half2t v;
        v[0] = (_Float16)W[k * 128 + c];          // coalesced in c
        v[1] = (_Float16)W[(k + 1) * 128 + c];
        *(half2t*)(dst + swz16(c, k >> 3) + ((k & 7) << 1)) = v;
    }
}

// Generic 128x128 MFMA gemm: out = postop(A @ W + bias). 256 thr = 4 waves, 64-row tiles,
// wave-private full-K rows -> no in-loop barriers. Grid ~192 so W-staging amortizes ~4 tiles.
template<typename TIN, typename TOUT, bool SSP_OUT, bool ZERO>
__global__ __launch_bounds__(256) void gemm_mfma_kernel(
    const TIN* __restrict__ A, const float* __restrict__ W,
    const float* __restrict__ bias, TOUT* __restrict__ out, int M,
    float* __restrict__ zbuf, int zcount4)
{
    __shared__ char sW[32768];
    const int t = threadIdx.x;
    const int w = t >> 6, lane = t & 63, m = lane & 15, q = lane >> 4;

    if (ZERO) {
        float4 z = {0.f, 0.f, 0.f, 0.f};
        for (int i = blockIdx.x * 256 + t; i < zcount4; i += gridDim.x * 256)
            ((float4*)zbuf)[i] = z;
    }
    stage_w<256>(W, sW, t);
    float bv[8];
    #pragma unroll
    for (int g = 0; g < 8; ++g) bv[g] = bias[g * 16 + m];
    __syncthreads();

    const floatx4 zero4 = {0.f, 0.f, 0.f, 0.f};
    const int ntiles = (M + 63) >> 6;
    for (int tile = blockIdx.x; tile < ntiles; tile += gridDim.x) {
        const int arow = tile * 64 + w * 16 + m;
        half8 a[4];
        if (arow < M) {
            const TIN* ap = A + (size_t)arow * 128;
            #pragma unroll
            for (int s = 0; s < 4; ++s) {
                if (sizeof(TIN) == 2) {
                    a[s] = *(const half8*)(ap + s * 32 + q * 8);
                } else {
                    float4 u0 = *(const float4*)((const float*)ap + s * 32 + q * 8);
                    float4 u1 = *(const float4*)((const float*)ap + s * 32 + q * 8 + 4);
                    a[s][0] = (_Float16)u0.x; a[s][1] = (_Float16)u0.y;
                    a[s][2] = (_Float16)u0.z; a[s][3] = (_Float16)u0.w;
                    a[s][4] = (_Float16)u1.x; a[s][5] = (_Float16)u1.y;
                    a[s][6] = (_Float16)u1.z; a[s][7] = (_Float16)u1.w;
                }
            }
        } else {
            #pragma unroll
            for (int s = 0; s < 4; ++s) a[s] = (half8){};
        }
        floatx4 acc[8];
        #pragma unroll
        for (int g = 0; g < 8; ++g) {
            floatx4 c = zero4;
            #pragma unroll
            for (int s = 0; s < 4; ++s) {
                half8 b = *(const half8*)(sW + swz16(g * 16 + m, 4 * s + q));
                c = __builtin_amdgcn_mfma_f32_16x16x32_f16(a[s], b, c, 0, 0, 0);
            }
            acc[g] = c;
        }
        #pragma unroll
        for (int r = 0; r < 4; ++r) {
            const int grow = tile * 64 + w * 16 + q * 4 + r;
            if (grow < M) {
                TOUT* op = out + (size_t)grow * 128;
                #pragma unroll
                for (int g = 0; g < 8; ++g) {
                    float v = acc[g][r] + bv[g];
                    if (SSP_OUT) v = sspf(v);
                    op[g * 16 + m] = (TOUT)v;
                }
            }
        }
    }
}

// Edge kernel v5: barrier-free + fully software-pipelined.
// All loads consumed in iteration t are ISSUED in iteration t-1 *before* its atomics,
// so no s_waitcnt ever has to drain outstanding atomics (vmcnt is count-ordered).
__global__ __launch_bounds__(256, 2) void edge_kernel(
    const float* __restrict__ f_ij, const float* __restrict__ rcut,
    const float* __restrict__ Wf1, const float* __restrict__ bf1,
    const float* __restrict__ Wf2, const float* __restrict__ bf2,
    const int* __restrict__ idx_i, const int* __restrict__ idx_j,
    const _Float16* __restrict__ h, float* __restrict__ agg)
{
    __shared__ char sW2[32768];
    __shared__ char sS[4][4096];   // wave-private 16-row fp16 slabs (swizzled)
    const int t = threadIdx.x;
    const int w = t >> 6, lane = t & 63, m = lane & 15, q = lane >> 4;

    stage_w<256>(Wf2, sW2, t);
    half8 bW1[8];
    #pragma unroll
    for (int g = 0; g < 8; ++g) {
        #pragma unroll
        for (int j = 0; j < 8; ++j) {
            int k = q * 8 + j;
            bW1[g][j] = (k < NRBF) ? (_Float16)Wf1[k * 128 + g * 16 + m] : (_Float16)0.0f;
        }
    }
    float bf1r[8], bf2r[8];
    #pragma unroll
    for (int g = 0; g < 8; ++g) { bf1r[g] = bf1[g * 16 + m]; bf2r[g] = bf2[g * 16 + m]; }
    __syncthreads();   // sW2 ready; no barriers after this

    char* mySS = sS[w];
    const floatx4 zero4 = {0.f, 0.f, 0.f, 0.f};
    const float4 fz = {0.f, 0.f, 0.f, 0.f};
    const int S = gridDim.x;

    int tl = blockIdx.x;
    // ---- prologue: state for tile tl ----
    float4 f0 = fz, f1 = fz;
    int4 ii4, jj4; float4 rc4;
    {
        const int e0 = tl * 64 + w * 16;
        const float* fb = f_ij + (size_t)(e0 + m) * NRBF + q * 8;
        if (q < 2)      { f0 = *(const float4*)fb; f1 = *(const float4*)(fb + 4); }
        else if (q == 2){ f0 = *(const float4*)fb; }
        ii4 = *(const int4*)&idx_i[e0 + q * 4];
        rc4 = *(const float4*)&rcut[e0 + q * 4];
        jj4 = *(const int4*)&idx_j[e0 + q * 4];
    }
    _Float16 hv[4][8];
    {
        int jj[4] = {jj4.x, jj4.y, jj4.z, jj4.w};
        #pragma unroll
        for (int r = 0; r < 4; ++r) {
            const _Float16* hp = h + (size_t)jj[r] * 128;
            #pragma unroll
            for (int g = 0; g < 8; ++g) hv[r][g] = hp[g * 16 + m];
        }
    }
    int4 jjv;   // idx_j VALUES for tile tl+S (gather addresses for next iteration)
    {
        const int nt = (tl + S < NTILES) ? tl + S : tl;
        jjv = *(const int4*)&idx_j[nt * 64 + w * 16 + q * 4];
    }

    for (; tl < NTILES; tl += S) {
        const int nx  = (tl + S     < NTILES) ? tl + S     : tl;
        const int nx2 = (tl + 2 * S < NTILES) ? tl + 2 * S : nx;

        // mm1 from pipelined f
        half8 a1;
        a1[0]=(_Float16)f0.x; a1[1]=(_Float16)f0.y; a1[2]=(_Float16)f0.z; a1[3]=(_Float16)f0.w;
        a1[4]=(_Float16)f1.x; a1[5]=(_Float16)f1.y; a1[6]=(_Float16)f1.z; a1[7]=(_Float16)f1.w;
        floatx4 c1[8];
        #pragma unroll
        for (int g = 0; g < 8; ++g)
            c1[g] = __builtin_amdgcn_mfma_f32_16x16x32_f16(a1, bW1[g], zero4, 0, 0, 0);

        // ssp + fp16 store to private slab (swizzled)
        #pragma unroll
        for (int g = 0; g < 8; ++g) {
            #pragma unroll
            for (int r = 0; r < 4; ++r) {
                float v = sspf(c1[g][r] + bf1r[g]);
                *(_Float16*)(mySS + swz16(q * 4 + r, 2 * g + (m >> 3)) + ((m & 7) << 1)) =
                    (_Float16)v;
            }
        }
        // A-frags back (same-wave rows, lgkmcnt orders)
        half8 a2[4];
        #pragma unroll
        for (int s = 0; s < 4; ++s)
            a2[s] = *(const half8*)(mySS + swz16(m, 4 * s + q));
        // mm2
        floatx4 acc[8];
        #pragma unroll
        for (int g = 0; g < 8; ++g) {
            floatx4 c = zero4;
            #pragma unroll
            for (int s = 0; s < 4; ++s) {
                half8 b = *(const half8*)(sW2 + swz16(g * 16 + m, 4 * s + q));
                c = __builtin_amdgcn_mfma_f32_16x16x32_f16(a2[s], b, c, 0, 0, 0);
            }
            acc[g] = c;
        }

        // ---- pre-atomic issue block: everything iteration t+1 will consume ----
        float4 nf0 = fz, nf1 = fz;
        {
            const int e0 = nx * 64 + w * 16;
            const float* fb = f_ij + (size_t)(e0 + m) * NRBF + q * 8;
            if (q < 2)      { nf0 = *(const float4*)fb; nf1 = *(const float4*)(fb + 4); }
            else if (q == 2){ nf0 = *(const float4*)fb; }
        }
        int4  nii4 = *(const int4*)&idx_i[nx * 64 + w * 16 + q * 4];
        float4 nrc4 = *(const float4*)&rcut[nx * 64 + w * 16 + q * 4];
        int4  njj  = *(const int4*)&idx_j[nx2 * 64 + w * 16 + q * 4];
        _Float16 nhv[4][8];
        {
            int jj[4] = {jjv.x, jjv.y, jjv.z, jjv.w};
            #pragma unroll
            for (int r = 0; r < 4; ++r) {
                const _Float16* hp = h + (size_t)jj[r] * 128;
                #pragma unroll
                for (int g = 0; g < 8; ++g) nhv[r][g] = hp[g * 16 + m];
            }
        }

        // ---- epilogue: atomics last; nothing after them waits on them ----
        int ii[4] = {ii4.x, ii4.y, ii4.z, ii4.w};
        float rc[4] = {rc4.x, rc4.y, rc4.z, rc4.w};
        #pragma unroll
        for (int r = 0; r < 4; ++r) {
            float* arow = agg + (size_t)ii[r] * 128;
            #pragma unroll
            for (int g = 0; g < 8; ++g) {
                float wij = (acc[g][r] + bf2r[g]) * rc[r];
                atomicAdd(&arow[g * 16 + m], (float)hv[r][g] * wij);
            }
        }

        // rotate pipeline state
        f0 = nf0; f1 = nf1; ii4 = nii4; rc4 = nrc4; jjv = njj;
        #pragma unroll
        for (int r = 0; r < 4; ++r)
            #pragma unroll
            for (int g = 0; g < 8; ++g) hv[r][g] = nhv[r][g];
    }
}

extern "C" void kernel_launch(void* const* d_in, const int* in_sizes, int n_in,
                              void* d_out, int out_size, void* d_ws, size_t ws_size,
                              hipStream_t stream) {
    const float* x     = (const float*)d_in[0];
    const float* f_ij  = (const float*)d_in[1];
    const float* rcutp = (const float*)d_in[2];
    const float* W_in  = (const float*)d_in[3];
    const float* b_in  = (const float*)d_in[4];
    const float* Wf1   = (const float*)d_in[5];
    const float* bf1   = (const float*)d_in[6];
    const float* Wf2   = (const float*)d_in[7];
    const float* bf2   = (const float*)d_in[8];
    const float* Wo1   = (const float*)d_in[9];
    const float* bo1   = (const float*)d_in[10];
    const float* Wo2   = (const float*)d_in[11];
    const float* bo2   = (const float*)d_in[12];
    const int* idx_i   = (const int*)d_in[13];
    const int* idx_j   = (const int*)d_in[14];
    float* out = (float*)d_out;

    float*     agg = (float*)d_ws;                                         // 25.6 MB fp32
    _Float16*  h   = (_Float16*)((char*)d_ws + (size_t)N_ATOMS * NF * 4);  // 12.8 MB fp16
    _Float16*  tmp = h;                                                    // h dead after edge

    const int zc4 = N_ATOMS * NF / 4;
    gemm_mfma_kernel<float, _Float16, false, true>
        <<<dim3(192), 256, 0, stream>>>(x, W_in, b_in, h, N_ATOMS, agg, zc4);
    edge_kernel<<<dim3(512), 256, 0, stream>>>(f_ij, rcutp, Wf1, bf1, Wf2, bf2,
                                               idx_i, idx_j, h, agg);
    gemm_mfma_kernel<float, _Float16, true, false>
        <<<dim3(192), 256, 0, stream>>>(agg, Wo1, bo1, tmp, N_ATOMS, nullptr, 0);
    gemm_mfma_kernel<_Float16, float, false, false>
        <<<dim3(192), 256, 0, stream>>>(tmp, Wo2, bo2, out, N_ATOMS, nullptr, 0);
}